// Round 4
// baseline (605.290 us; speedup 1.0000x reference)
//
#include <hip/hip_runtime.h>
#include <hip/hip_fp16.h>
#include <math.h>

// Workspace layout (floats)
#define WS_FLAT 0                      // 65536   pooled+flattened p4
#define WS_PART 65536                  // 524288  gemm1 split-K partials (256 x 2048)
#define WS_H1   (65536 + 524288)       // 2048
#define WS_H2   (WS_H1 + 2048)         // 4096
#define WS_POLY (WS_H2 + 4096)         // 8000    current polygons [4][20][50][2]
#define WS_P2T  1048576                // __half p2t [4][65536 px][256 ch] = 134 MB

// ---------------- Kernel 0: fused [transpose p2 CHW fp32 -> HWC fp16] + [pool p4]
// blocks 0..16383: transpose tile; blocks 16384..16639: adaptive-avg-pool
__global__ void __launch_bounds__(256) fused0_k(const float* __restrict__ p2,
                                                __half* __restrict__ p2th,
                                                const float* __restrict__ p4,
                                                float* __restrict__ flat) {
    __shared__ float t[64][65];   // [px_local][c_local]
    int tid = threadIdx.x;
    if (blockIdx.x < 16384) {
        int tile = blockIdx.x;
        int b  = tile >> 12;
        int ct = (tile >> 10) & 3;
        int xt = tile & 1023;
        int c0 = ct << 6, yx0 = xt << 6;
        // load: lanes sweep px (contiguous float4), rows sweep c
        int jv = (tid & 15) << 2;
        int i0 = tid >> 4;
        const float* ip = p2 + (((size_t)(b * 256 + c0)) << 16) + yx0;
        #pragma unroll
        for (int ii = i0; ii < 64; ii += 16) {
            float4 v = *(const float4*)(ip + ((size_t)ii << 16) + jv);
            t[jv + 0][ii] = v.x; t[jv + 1][ii] = v.y;
            t[jv + 2][ii] = v.z; t[jv + 3][ii] = v.w;
        }
        __syncthreads();
        // store: thread = (c-group tid&7 -> 8 ch, px row tid>>3, +32)
        int cl = (tid & 7) << 3;
        #pragma unroll
        for (int jj = tid >> 3; jj < 64; jj += 32) {
            union { __half h[8]; float4 f; } u;
            #pragma unroll
            for (int q = 0; q < 8; ++q) u.h[q] = __float2half(t[jj][cl + q]);
            *(float4*)(p2th + ((size_t)b << 24) + ((size_t)(yx0 + jj) << 8) + c0 + cl) = u.f;
        }
    } else {
        int o = (blockIdx.x - 16384) * 256 + tid;   // 65536 outputs
        int b = o >> 14;
        int c = (o >> 6) & 255;
        int ij = o & 63;
        int i = ij >> 3, j = ij & 7;
        const float* base = p4 + (((size_t)(b * 256 + c) * 64 + i * 8) * 64 + j * 8);
        float s = 0.f;
        #pragma unroll
        for (int u = 0; u < 8; ++u) {
            const float4* r = (const float4*)(base + u * 64);
            float4 a = r[0], bb = r[1];
            s += a.x + a.y + a.z + a.w + bb.x + bb.y + bb.z + bb.w;
        }
        flat[o] = s * (1.0f / 64.0f);
    }
}

// ---------------- Kernel 2a: GEMM1 split-K: flat[4,16384] @ iw1[16384,512]
__global__ void g1a_k(const float* __restrict__ flat, const float* __restrict__ iw1,
                      float* __restrict__ part) {
    __shared__ float sf[4][64];
    int tid = threadIdx.x;
    int kbase = blockIdx.x * 64;
    if (tid < 256) sf[tid >> 6][tid & 63] = flat[(tid >> 6) * 16384 + kbase + (tid & 63)];
    __syncthreads();
    float a0 = 0.f, a1 = 0.f, a2 = 0.f, a3 = 0.f;
    for (int k = 0; k < 64; ++k) {
        float w = iw1[(size_t)(kbase + k) * 512 + tid];
        a0 = fmaf(sf[0][k], w, a0);
        a1 = fmaf(sf[1][k], w, a1);
        a2 = fmaf(sf[2][k], w, a2);
        a3 = fmaf(sf[3][k], w, a3);
    }
    float* pp = part + (size_t)blockIdx.x * 2048;
    pp[tid] = a0; pp[512 + tid] = a1; pp[1024 + tid] = a2; pp[1536 + tid] = a3;
}

// ---------------- Kernel 2b: reduce partials -> h1 (+bias, relu)
__global__ void g1b_k(const float* __restrict__ part, const float* __restrict__ ib1,
                      float* __restrict__ h1) {
    __shared__ float red[8][32];
    int tid = threadIdx.x;
    int cc = tid >> 5, oo = tid & 31;
    int o = blockIdx.x * 32 + oo;
    float s = 0.f;
    for (int i = 0; i < 32; ++i)
        s += part[(size_t)(cc + 8 * i) * 2048 + o];
    red[cc][oo] = s;
    __syncthreads();
    if (cc == 0) {
        float t = 0.f;
        #pragma unroll
        for (int c2 = 0; c2 < 8; ++c2) t += red[c2][oo];
        t += ib1[o & 511];
        h1[o] = fmaxf(t, 0.f);
    }
}

// ---------------- Kernel 3: GEMM2
__global__ void g2_k(const float* __restrict__ h1, const float* __restrict__ iw2,
                     const float* __restrict__ ib2, float* __restrict__ h2) {
    __shared__ float sh[512];
    __shared__ float red[4][64];
    int tid = threadIdx.x;
    int b = blockIdx.x >> 4, jt = blockIdx.x & 15;
    sh[tid] = h1[b * 512 + tid];
    sh[tid + 256] = h1[b * 512 + 256 + tid];
    __syncthreads();
    int j = (jt << 6) + (tid & 63);
    int kc = tid >> 6;
    float acc = 0.f;
    for (int k = kc * 128; k < kc * 128 + 128; ++k)
        acc = fmaf(sh[k], iw2[(size_t)k * 1024 + j], acc);
    red[kc][tid & 63] = acc;
    __syncthreads();
    if (kc == 0) {
        float t = red[0][tid] + red[1][tid] + red[2][tid] + red[3][tid] + ib2[j];
        h2[b * 1024 + j] = fmaxf(t, 0.f);
    }
}

// ---------------- Kernel 4: GEMM3 -> sigmoid -> init polys
__global__ void g3_k(const float* __restrict__ h2, const float* __restrict__ iw3,
                     const float* __restrict__ ib3, float* __restrict__ out_init,
                     float* __restrict__ poly) {
    __shared__ float sh[1024];
    __shared__ float red[4][64];
    int tid = threadIdx.x;
    int b = blockIdx.x >> 5, jt = blockIdx.x & 31;
    const float* h = h2 + b * 1024;
    sh[tid] = h[tid]; sh[tid + 256] = h[tid + 256];
    sh[tid + 512] = h[tid + 512]; sh[tid + 768] = h[tid + 768];
    __syncthreads();
    int j = (jt << 6) + (tid & 63);
    int kc = tid >> 6;
    float acc = 0.f;
    if (j < 2000) {
        for (int k = kc * 256; k < kc * 256 + 256; ++k)
            acc = fmaf(sh[k], iw3[(size_t)k * 2000 + j], acc);
    }
    red[kc][tid & 63] = acc;
    __syncthreads();
    if (kc == 0 && j < 2000) {
        float t = red[0][tid] + red[1][tid] + red[2][tid] + red[3][tid] + ib3[j];
        float s = 1.f / (1.f + expf(-t));
        int o = b * 2000 + j;
        out_init[o] = s;
        poly[o] = s;
    }
}

// ---------------- Kernel 5: refinement step, 8 pts/block, 500 blocks (2 blk/CU)
// thread = (jc = tid&63 -> 4 cols, pg = tid>>6 -> pts pg*2, pg*2+1)
__global__ void __launch_bounds__(256) step_k(
    const __half* __restrict__ p2th,
    const float* __restrict__ rw1, const float* __restrict__ rb1,
    const float* __restrict__ rw2, const float* __restrict__ rb2,
    const float* __restrict__ rw3, const float* __restrict__ rb3,
    float* __restrict__ poly) {
    __shared__ __align__(16) float s_inp[258 * 8];   // [k][pt]  (reads broadcast)
    __shared__ __align__(16) float s_r1[8 * 256];    // [pt][j]  (writes contiguous)
    __shared__ __align__(16) float s_r2[8 * 132];    // [pt][j]  padded for r3 reads
    int tid = threadIdx.x;
    int pt0 = blockIdx.x * 8;
    int b = pt0 / 1000;                 // 8 | 1000: whole block same batch
    const __half* bt = p2th + ((size_t)b << 24);

    // ---- gather: thread = (ch-pair tid&127, pt-group tid>>7 -> 4 pts)
    {
        int ch2 = (tid & 127) << 1;
        int pgg = tid >> 7;
        float v0[4], v1[4];
        #pragma unroll
        for (int pp = 0; pp < 4; ++pp) {
            int pt = pt0 + pgg * 4 + pp;
            float cx = poly[pt * 2], cy = poly[pt * 2 + 1];
            float ix = fminf(fmaxf(cx * 256.f - 0.5f, 0.f), 255.f);
            float iy = fminf(fmaxf(cy * 256.f - 0.5f, 0.f), 255.f);
            float x0f = floorf(ix), y0f = floorf(iy);
            int x0 = (int)x0f, y0 = (int)y0f;
            int x1 = min(x0 + 1, 255), y1 = min(y0 + 1, 255);
            float wx = ix - x0f, wy = iy - y0f;
            int r0 = (y0 << 16) + (x0 << 8) + ch2;
            int r1a = (y1 << 16) + (x0 << 8) + ch2;
            int dx = (x1 - x0) << 8;
            float2 f00 = __half22float2(*(const __half2*)(bt + r0));
            float2 f01 = __half22float2(*(const __half2*)(bt + r0 + dx));
            float2 f10 = __half22float2(*(const __half2*)(bt + r1a));
            float2 f11 = __half22float2(*(const __half2*)(bt + r1a + dx));
            float t0 = f00.x + (f01.x - f00.x) * wx;
            float b0 = f10.x + (f11.x - f10.x) * wx;
            float t1 = f00.y + (f01.y - f00.y) * wx;
            float b1 = f10.y + (f11.y - f10.y) * wx;
            v0[pp] = t0 + (b0 - t0) * wy;
            v1[pp] = t1 + (b1 - t1) * wy;
        }
        *(float4*)&s_inp[ch2 * 8 + pgg * 4] = make_float4(v0[0], v0[1], v0[2], v0[3]);
        *(float4*)&s_inp[(ch2 + 1) * 8 + pgg * 4] = make_float4(v1[0], v1[1], v1[2], v1[3]);
        if (tid < 16) {  // coord rows 256,257
            int p = tid >> 1, d = tid & 1;
            s_inp[(256 + d) * 8 + p] = poly[(pt0 + p) * 2 + d];
        }
    }
    __syncthreads();

    int jc = tid & 63, pg = tid >> 6;

    // ---- r1 = relu(inp @ rw1 + rb1): 4 cols x 2 pts per thread
    {
        float4 bias = *(const float4*)(rb1 + jc * 4);
        float4 accA = bias, accB = bias;
        for (int k = 0; k < 258; ++k) {
            float2 a = *(const float2*)&s_inp[k * 8 + pg * 2];    // broadcast
            float4 w = *(const float4*)(rw1 + k * 256 + jc * 4);  // coalesced
            accA.x = fmaf(a.x, w.x, accA.x); accA.y = fmaf(a.x, w.y, accA.y);
            accA.z = fmaf(a.x, w.z, accA.z); accA.w = fmaf(a.x, w.w, accA.w);
            accB.x = fmaf(a.y, w.x, accB.x); accB.y = fmaf(a.y, w.y, accB.y);
            accB.z = fmaf(a.y, w.z, accB.z); accB.w = fmaf(a.y, w.w, accB.w);
        }
        accA.x = fmaxf(accA.x, 0.f); accA.y = fmaxf(accA.y, 0.f);
        accA.z = fmaxf(accA.z, 0.f); accA.w = fmaxf(accA.w, 0.f);
        accB.x = fmaxf(accB.x, 0.f); accB.y = fmaxf(accB.y, 0.f);
        accB.z = fmaxf(accB.z, 0.f); accB.w = fmaxf(accB.w, 0.f);
        *(float4*)&s_r1[(pg * 2 + 0) * 256 + jc * 4] = accA;  // contiguous per wave
        *(float4*)&s_r1[(pg * 2 + 1) * 256 + jc * 4] = accB;
    }
    __syncthreads();

    // ---- r2 = relu(r1 @ rw2 + rb2): 2 cols x 2 pts per thread
    {
        const float* rA = &s_r1[(pg * 2 + 0) * 256];
        const float* rB = &s_r1[(pg * 2 + 1) * 256];
        float2 bias = *(const float2*)(rb2 + jc * 2);
        float2 dA = bias, dB = bias;
        for (int k = 0; k < 256; ++k) {
            float aA = rA[k], aB = rB[k];                         // broadcast
            float2 w = *(const float2*)(rw2 + k * 128 + jc * 2);  // coalesced
            dA.x = fmaf(aA, w.x, dA.x); dA.y = fmaf(aA, w.y, dA.y);
            dB.x = fmaf(aB, w.x, dB.x); dB.y = fmaf(aB, w.y, dB.y);
        }
        dA.x = fmaxf(dA.x, 0.f); dA.y = fmaxf(dA.y, 0.f);
        dB.x = fmaxf(dB.x, 0.f); dB.y = fmaxf(dB.y, 0.f);
        *(float2*)&s_r2[(pg * 2 + 0) * 132 + jc * 2] = dA;
        *(float2*)&s_r2[(pg * 2 + 1) * 132 + jc * 2] = dB;
    }
    __syncthreads();

    // ---- r3 -> tanh -> scaled clip -> polygon update (16 outputs: 8 pts x 2)
    if (tid < 16) {
        int p = tid >> 1, d = tid & 1;
        float acc = rb3[d];
        for (int k = 0; k < 128; ++k)
            acc = fmaf(s_r2[p * 132 + k], rw3[k * 2 + d], acc);
        float disp = tanhf(acc) * 0.08f;
        disp = fminf(fmaxf(disp, -0.16f), 0.16f);
        int idx = (pt0 + p) * 2 + d;
        float nv = poly[idx] + disp;
        poly[idx] = fminf(fmaxf(nv, 0.f), 1.f);
    }
}

// ---------------- Kernel 6: validity head + final polygon copy
__global__ void valid_k(const float* __restrict__ poly,
                        const float* __restrict__ vw1, const float* __restrict__ vb1,
                        const float* __restrict__ vw2, const float* __restrict__ vb2,
                        float* __restrict__ out) {
    __shared__ float sp[100];
    __shared__ float sred[2];
    int tid = threadIdx.x;  // 128
    int row = blockIdx.x;   // 80
    if (tid < 100) {
        float v = poly[row * 100 + tid];
        sp[tid] = v;
        out[row * 100 + tid] = v;
    }
    __syncthreads();
    float acc = vb1[tid];
    for (int k = 0; k < 100; ++k)
        acc = fmaf(sp[k], vw1[k * 128 + tid], acc);
    float pr = fmaxf(acc, 0.f) * vw2[tid];
    #pragma unroll
    for (int off = 32; off > 0; off >>= 1)
        pr += __shfl_down(pr, off, 64);
    if ((tid & 63) == 0) sred[tid >> 6] = pr;
    __syncthreads();
    if (tid == 0) {
        float s = sred[0] + sred[1] + vb2[0];
        out[8000 + row] = 1.f / (1.f + expf(-s));
    }
}

extern "C" void kernel_launch(void* const* d_in, const int* in_sizes, int n_in,
                              void* d_out, int out_size, void* d_ws, size_t ws_size,
                              hipStream_t stream) {
    const float* p2  = (const float*)d_in[0];
    const float* p4  = (const float*)d_in[1];
    const float* iw1 = (const float*)d_in[2];
    const float* ib1 = (const float*)d_in[3];
    const float* iw2 = (const float*)d_in[4];
    const float* ib2 = (const float*)d_in[5];
    const float* iw3 = (const float*)d_in[6];
    const float* ib3 = (const float*)d_in[7];
    const float* rw1 = (const float*)d_in[8];
    const float* rb1 = (const float*)d_in[9];
    const float* rw2 = (const float*)d_in[10];
    const float* rb2 = (const float*)d_in[11];
    const float* rw3 = (const float*)d_in[12];
    const float* rb3 = (const float*)d_in[13];
    const float* vw1 = (const float*)d_in[14];
    const float* vb1 = (const float*)d_in[15];
    const float* vw2 = (const float*)d_in[16];
    const float* vb2 = (const float*)d_in[17];
    float* out = (float*)d_out;
    float* ws = (float*)d_ws;
    float* flat = ws + WS_FLAT;
    float* part = ws + WS_PART;
    float* h1   = ws + WS_H1;
    float* h2   = ws + WS_H2;
    float* poly = ws + WS_POLY;
    __half* p2th = (__half*)(ws + WS_P2T);

    fused0_k<<<16640, 256, 0, stream>>>(p2, p2th, p4, flat);  // transpose + pool
    g1a_k<<<256, 512, 0, stream>>>(flat, iw1, part);
    g1b_k<<<64, 256, 0, stream>>>(part, ib1, h1);
    g2_k<<<64, 256, 0, stream>>>(h1, iw2, ib2, h2);
    g3_k<<<128, 256, 0, stream>>>(h2, iw3, ib3, out + 8080, poly);
    for (int s = 0; s < 3; ++s)
        step_k<<<500, 256, 0, stream>>>(p2th, rw1, rb1, rw2, rb2, rw3, rb3, poly);
    valid_k<<<80, 128, 0, stream>>>(poly, vw1, vb1, vw2, vb2, out);
}